// Round 20
// baseline (33.266 us; speedup 1.0000x reference)
//
#include <hip/hip_runtime.h>
#include <hip/hip_bf16.h>

#define L_SEQ 1024
#define NT 32          // number of 32-row KV tiles

typedef __attribute__((ext_vector_type(8))) __bf16 bf16x8;
typedef __attribute__((ext_vector_type(4))) __bf16 bf16x4;
typedef __attribute__((ext_vector_type(4))) float f32x4;

__device__ __forceinline__ float fast_exp2(float x) {
#if __has_builtin(__builtin_amdgcn_exp2f)
    return __builtin_amdgcn_exp2f(x);
#else
    return exp2f(x);
#endif
}

#define MFMA16(a, b, c) __builtin_amdgcn_mfma_f32_16x16x32_bf16((a), (b), (c), 0, 0, 0)

// ---------------------------------------------------------------------------
// Round 20: push the waves-per-staged-tile lever to 16.
// 256 blocks x 1024 threads (16 waves), 256 q-rows/block -> exactly 1
// block/CU, 16 waves/CU (same as R18/R19) but HALF the staging streams per
// CU: each batch's K/V now staged by 4 blocks instead of 8. Role-split
// staging (wave-uniform): waves 0-7 stage K (1 float4/thread, R12 image),
// waves 8-15 stage V column-wise (4 f32/thread, R19's conflict-free b64
// map). Body = R19 verbatim: 16 q-rows/wave, de-fenced, no-max exp2
// softmax (NBIAS in acc init), ones-MFMA l, single lgkmcnt(0)+barrier/iter.
// ---------------------------------------------------------------------------
__global__ __launch_bounds__(1024) void sdpa_fused(
    const float* __restrict__ Q, const float* __restrict__ K,
    const float* __restrict__ V, float* __restrict__ O)
{
    __shared__ __align__(16) char lds[2 * 8192];

    const int tid  = threadIdx.x;
    const int lane = tid & 63;
    const int wave = tid >> 6;       // 0..15
    const int li   = lane & 15;
    const int h    = lane >> 4;

    // XCD-chunked swizzle: 32 consecutive logical blocks per XCD.
    const int wg = blockIdx.x;
    const int lb = (wg & 7) * 32 + (wg >> 3);
    const int b  = lb >> 2;          // batch
    const int qt = lb & 3;           // 256-row q-tile
    const int q0 = qt * 256 + wave * 16 + li;   // 16 waves cover 256 rows

    const float* Qb = Q + (size_t)b * L_SEQ * 64;
    const char*  Kb = (const char*)(K + (size_t)b * L_SEQ * 64);
    const float* Vf = V + (size_t)b * L_SEQ * 64;

    // ---- staging role (wave-uniform): waves 0-7 -> K, waves 8-15 -> V
    const bool kstager = (tid < 512);
    int wd;            // LDS dest byte offset within buffer
    int vd = 0, vrow = 0;
    if (kstager) {
        const int qi = tid;                    // quad index 0..511
        const int r  = qi >> 4;                // kv row 0..31
        const int d4 = (qi & 15) << 2;         // d 0..60
        const int c32 = d4 >> 5, rem = d4 & 31, hf = rem >> 4, hh = (rem & 15) >> 2;
        wd = r * 128 + 2 * (((c32 * 32 + hh * 8) ^ ((r & 7) * 8)) + hf * 4);
    } else {
        const int vt = tid - 512;              // 0..511
        vd   = vt & 63;                        // d column this thread owns
        vrow = (vt >> 6) * 4;                  // rows vrow..vrow+3
        wd = 4096 + vd * 64 + 8 * ((vt >> 6) ^ ((vd >> 1) & 7));
    }

    // ---- Q fragments (single q-block): fold (1/temperature)*log2(e)
    const float QSC = 0.18033688011112042f;   // 0.125 * log2(e)
    bf16x8 qf0, qf1;
    {
        const float* ra = &Qb[(size_t)q0 * 64];
        f32x4 a00 = *(const f32x4*)&ra[0  + h * 4];
        f32x4 a01 = *(const f32x4*)&ra[16 + h * 4];
        f32x4 a10 = *(const f32x4*)&ra[32 + h * 4];
        f32x4 a11 = *(const f32x4*)&ra[48 + h * 4];
        #pragma unroll
        for (int j = 0; j < 4; ++j) {
            qf0[j]     = (__bf16)(a00[j] * QSC);
            qf0[4 + j] = (__bf16)(a01[j] * QSC);
            qf1[j]     = (__bf16)(a10[j] * QSC);
            qf1[4 + j] = (__bf16)(a11[j] * QSC);
        }
    }

    bf16x8 ones;
    #pragma unroll
    for (int j = 0; j < 8; ++j) ones[j] = (__bf16)1.0f;

    const float NBIAS = -46.0f;   // log2-domain bias, cancels in O = PV/l
    f32x4 o0 = {0.f,0.f,0.f,0.f}, o1 = {0.f,0.f,0.f,0.f};
    f32x4 o2 = {0.f,0.f,0.f,0.f}, o3 = {0.f,0.f,0.f,0.f};
    f32x4 ol = {0.f,0.f,0.f,0.f};

    // ---- reg-staging: one 16B quad (K) or 4 column f32 (V) per thread
    f32x4 sk0;
    auto load = [&](int t) {
        if (kstager) {
            sk0 = *(const f32x4*)(Kb + (size_t)t * 8192 + (tid << 4));
        } else {
            const float* vcol = Vf + (size_t)t * 2048 + (size_t)vrow * 64 + vd;
            #pragma unroll
            for (int u = 0; u < 4; ++u) sk0[u] = vcol[u * 64];
        }
    };
    auto writebuf = [&](int bi) {
        bf16x4 a;
        #pragma unroll
        for (int j = 0; j < 4; ++j) a[j] = (__bf16)sk0[j];
        *(bf16x4*)(lds + bi * 8192 + wd) = a;
    };

    const int kswz = (li & 7) << 4;
    const int swr  = (li >> 1) & 7;
    const int vo   = (h ^ swr) << 3;

    auto body = [&](int bi) {
        const char* bb = lds + bi * 8192;
        // K fragments (swizzled image)
        bf16x8 kf00 = *(const bf16x8*)(bb + li * 128 + ((h * 16) ^ kswz));
        bf16x8 kf01 = *(const bf16x8*)(bb + li * 128 + ((64 + h * 16) ^ kswz));
        bf16x8 kf10 = *(const bf16x8*)(bb + 2048 + li * 128 + ((h * 16) ^ kswz));
        bf16x8 kf11 = *(const bf16x8*)(bb + 2048 + li * 128 + ((64 + h * 16) ^ kswz));
        // V^T fragments: per chunk, 2 x ds_read_b64 (conflict-free, R15 map)
        bf16x8 vf[4];
        #pragma unroll
        for (int dc = 0; dc < 4; ++dc) {
            const char* vbase = bb + 4096 + (dc * 16 + li) * 64;
            bf16x4 lo = *(const bf16x4*)(vbase + vo);
            bf16x4 hi = *(const bf16x4*)(vbase + (vo ^ 32));
            vf[dc] = __builtin_shufflevector(lo, hi, 0, 1, 2, 3, 4, 5, 6, 7);
        }
        // de-fenced: compiler emits fine-grained lgkmcnt(N) per MFMA operand

        // ---- QK^T (bias pre-loaded in accumulator)
        const f32x4 nb = {NBIAS, NBIAS, NBIAS, NBIAS};
        f32x4 s0 = MFMA16(kf01, qf1, MFMA16(kf00, qf0, nb));
        f32x4 s1 = MFMA16(kf11, qf1, MFMA16(kf10, qf0, nb));

        // ---- exponentiate (no max, no cross-lane): p = 2^(s - 46)
        bf16x8 pf;
        #pragma unroll
        for (int r = 0; r < 4; ++r) {
            pf[r]     = (__bf16)fast_exp2(s0[r]);
            pf[4 + r] = (__bf16)fast_exp2(s1[r]);
        }

        // ---- PV + l via ones-MFMA
        o0 = MFMA16(vf[0], pf, o0);
        o1 = MFMA16(vf[1], pf, o1);
        o2 = MFMA16(vf[2], pf, o2);
        o3 = MFMA16(vf[3], pf, o3);
        ol = MFMA16(ones, pf, ol);
    };

    // end-of-iteration ordering point (single fence per iter)
    auto fence_barrier = [&]() {
        asm volatile("s_waitcnt lgkmcnt(0)" ::: "memory");
        __builtin_amdgcn_s_barrier();
    };

    // ---- prologue: tile 0 staged, tile 1 loads in flight
    load(0);
    writebuf(0);
    load(1);
    fence_barrier();

    #pragma unroll 2
    for (int t = 0; t < NT - 2; ++t) {
        writebuf((t + 1) & 1);   // write tile t+1 (regs; auto vmcnt waits)
        load(t + 2);             // issue tile t+2 loads
        body(t & 1);             // compute tile t
        fence_barrier();
    }
    // t = 30: write tile 31, no more loads
    writebuf(31 & 1);
    body(30 & 1);
    fence_barrier();
    // t = 31
    body(31 & 1);

    // ---- finalize: l replicated in ol[r] (ones-MFMA)
    const float inv_l = 1.f / ol[0];

    float* Ob = O + ((size_t)b * L_SEQ + q0) * 64;
    f32x4 ov;
    #pragma unroll
    for (int r = 0; r < 4; ++r) ov[r] = o0[r] * inv_l;
    *(f32x4*)&Ob[0 * 16 + h * 4] = ov;
    #pragma unroll
    for (int r = 0; r < 4; ++r) ov[r] = o1[r] * inv_l;
    *(f32x4*)&Ob[1 * 16 + h * 4] = ov;
    #pragma unroll
    for (int r = 0; r < 4; ++r) ov[r] = o2[r] * inv_l;
    *(f32x4*)&Ob[2 * 16 + h * 4] = ov;
    #pragma unroll
    for (int r = 0; r < 4; ++r) ov[r] = o3[r] * inv_l;
    *(f32x4*)&Ob[3 * 16 + h * 4] = ov;
}

extern "C" void kernel_launch(void* const* d_in, const int* in_sizes, int n_in,
                              void* d_out, int out_size, void* d_ws, size_t ws_size,
                              hipStream_t stream) {
    const float* q = (const float*)d_in[0];
    const float* k = (const float*)d_in[1];
    const float* v = (const float*)d_in[2];
    float* o = (float*)d_out;

    sdpa_fused<<<dim3(256), dim3(1024), 0, stream>>>(q, k, v, o);
}